// Round 1
// baseline (577.308 us; speedup 1.0000x reference)
//
#include <hip/hip_runtime.h>
#include <hip/hip_bf16.h>
#include <math.h>

#define Bn 256
#define Mn 196
#define Dn 512
#define Kpad 224      // 7 k-steps of 32 (m 196..223 zero-padded)
#define Mstr 232      // LDS col stride (elems): 464B = 29 x 16B granules (odd) -> even bank spread
#define TILE 128
#define OUTB 131328   // 512*513/2

typedef __attribute__((ext_vector_type(8))) short bf16x8;
typedef __attribute__((ext_vector_type(4))) float f32x4;

__device__ __forceinline__ unsigned short f2bf(float f) {
  unsigned u = __float_as_uint(f);
  unsigned r = u + 0x7fffu + ((u >> 16) & 1u);
  return (unsigned short)(r >> 16);
}

// Stage a 128-col panel of x_b transposed into LDS as bf16 [col][m], m zero-padded to 224.
// Also accumulates per-(thread) partial sum of x^2 into dtmp (fp32 diag).
__device__ __forceinline__ void stage_panel(short* __restrict__ lds,
                                            float* __restrict__ dtmp,
                                            const float* __restrict__ xb,
                                            int c0, int tid) {
  const int c = tid & 127;
  const int half = tid >> 7;
  float dacc = 0.f;
  #pragma unroll 4
  for (int it = 0; it < 56; ++it) {
    const int mp = half + 2 * it;       // pair index 0..111
    const int m0 = mp * 2;
    float x0 = (m0 < Mn)     ? xb[(size_t)m0 * Dn + c0 + c]       : 0.f;
    float x1 = (m0 + 1 < Mn) ? xb[(size_t)(m0 + 1) * Dn + c0 + c] : 0.f;
    dacc += x0 * x0 + x1 * x1;
    unsigned pack = ((unsigned)f2bf(x1) << 16) | (unsigned)f2bf(x0);
    *reinterpret_cast<unsigned*>(&lds[c * Mstr + m0]) = pack;
  }
  dtmp[tid] = dacc;
}

__global__ __launch_bounds__(256)
void k1_gram_dcov(const float* __restrict__ x, const float* __restrict__ tptr,
                  float* __restrict__ out, float* __restrict__ rowsum) {
  __shared__ short ldsI[TILE * Mstr];
  __shared__ short ldsJ[TILE * Mstr];
  __shared__ float dtmp[256];
  __shared__ float dI[TILE];
  __shared__ float dJ[TILE];

  const int tid = threadIdx.x;
  const int bid = blockIdx.x;
  const int ti  = bid >> 8;    // 0..3  (heavy ti=0 blocks dispatch first)
  const int b   = bid & 255;
  const float* xb = x + (size_t)b * Mn * Dn;
  const float et = expf(tptr[0]);

  stage_panel(ldsI, dtmp, xb, ti * TILE, tid);
  __syncthreads();
  if (tid < TILE) dI[tid] = dtmp[tid] + dtmp[tid + 128];
  __syncthreads();

  const int lane = tid & 63;
  const int wid  = tid >> 6;
  const int wi = wid >> 1, wj = wid & 1;   // 2x2 waves of 64x64
  const int lr = lane & 15, lg = lane >> 4;
  const size_t outb = (size_t)b * OUTB;

  for (int tj = ti; tj < 4; ++tj) {
    const short* Bp;
    const float* dJv;
    if (tj > ti) {
      stage_panel(ldsJ, dtmp, xb, tj * TILE, tid);
      __syncthreads();
      if (tid < TILE) dJ[tid] = dtmp[tid] + dtmp[tid + 128];
      __syncthreads();
      Bp = ldsJ; dJv = dJ;
    } else {
      Bp = ldsI; dJv = dI;
    }

    // ---- MFMA: 64x64 per wave, K = 224 ----
    f32x4 acc[4][4];
    #pragma unroll
    for (int a = 0; a < 4; ++a)
      #pragma unroll
      for (int c = 0; c < 4; ++c) acc[a][c] = (f32x4){0.f, 0.f, 0.f, 0.f};

    #pragma unroll
    for (int kk = 0; kk < 7; ++kk) {
      const int k0 = kk * 32 + lg * 8;
      bf16x8 af[4], bfr[4];
      #pragma unroll
      for (int mi = 0; mi < 4; ++mi)
        af[mi] = *reinterpret_cast<const bf16x8*>(&ldsI[(wi * 64 + mi * 16 + lr) * Mstr + k0]);
      #pragma unroll
      for (int nj = 0; nj < 4; ++nj)
        bfr[nj] = *reinterpret_cast<const bf16x8*>(&Bp[(wj * 64 + nj * 16 + lr) * Mstr + k0]);
      #pragma unroll
      for (int mi = 0; mi < 4; ++mi)
        #pragma unroll
        for (int nj = 0; nj < 4; ++nj)
          acc[mi][nj] = __builtin_amdgcn_mfma_f32_16x16x32_bf16(af[mi], bfr[nj], acc[mi][nj], 0, 0, 0);
    }

    // ---- epilogue: dcov, triu store, symmetric row/col sum accumulation ----
    float colAcc[4] = {0.f, 0.f, 0.f, 0.f};
    #pragma unroll
    for (int mi = 0; mi < 4; ++mi) {
      #pragma unroll
      for (int reg = 0; reg < 4; ++reg) {
        const int iloc = wi * 64 + mi * 16 + lg * 4 + reg;
        const int ig = ti * TILE + iloc;
        float rowAcc = 0.f;
        #pragma unroll
        for (int nj = 0; nj < 4; ++nj) {
          const int jloc = wj * 64 + nj * 16 + lr;
          const int jg = tj * TILE + jloc;
          float g = acc[mi][nj][reg];
          float raw = dI[iloc] + dJv[jloc] - 2.f * g;
          raw = fmaxf(raw, 0.f);
          if (ig == jg) raw = 0.f;                 // exact-0 diagonal (matches reference)
          const float v = sqrtf(et * raw + 1e-5f);
          if (ig <= jg) {
            const int off = ig * Dn - (ig * (ig - 1)) / 2;
            out[outb + off + (jg - ig)] = v;
            rowAcc += v;                           // row i gets all j>=i on this tile
            if (ig < jg) colAcc[nj] += v;          // col j gets strict-upper (symmetry)
          }
        }
        rowAcc += __shfl_xor(rowAcc, 1);
        rowAcc += __shfl_xor(rowAcc, 2);
        rowAcc += __shfl_xor(rowAcc, 4);
        rowAcc += __shfl_xor(rowAcc, 8);
        if (lr == 0) atomicAdd(&rowsum[b * Dn + ig], rowAcc);
      }
    }
    #pragma unroll
    for (int nj = 0; nj < 4; ++nj) {
      float cs = colAcc[nj];
      cs += __shfl_xor(cs, 16);
      cs += __shfl_xor(cs, 32);
      if (lg == 0) {
        const int jg = tj * TILE + wj * 64 + nj * 16 + lr;
        atomicAdd(&rowsum[b * Dn + jg], cs);
      }
    }
    __syncthreads();   // protect ldsJ/dtmp before next stage
  }
}

__global__ __launch_bounds__(256)
void k2a_tot(const float* __restrict__ rowsum, float* __restrict__ tot) {
  const int b = blockIdx.x;
  const int t = threadIdx.x;
  float v = rowsum[b * Dn + t] + rowsum[b * Dn + t + 256];
  #pragma unroll
  for (int m = 1; m < 64; m <<= 1) v += __shfl_xor(v, m);
  __shared__ float w[4];
  if ((t & 63) == 0) w[t >> 6] = v;
  __syncthreads();
  if (t == 0) tot[b] = w[0] + w[1] + w[2] + w[3];
}

__global__ __launch_bounds__(256)
void k2_center(float* __restrict__ out, const float* __restrict__ rowsum,
               const float* __restrict__ tot) {
  const int i = blockIdx.x;     // row 0..511
  const int b = blockIdx.y;     // batch
  const int t = threadIdx.x;
  const float inv = 1.f / 512.f;
  const float itot = tot[b] * (1.f / (512.f * 512.f));
  const float ri = rowsum[b * Dn + i] * inv;
  const int L = Dn - i;
  const size_t base = (size_t)b * OUTB + (size_t)(i * Dn - (i * (i - 1)) / 2);
  for (int s = t; s < L; s += 256) {
    const int j = i + s;
    const float v = out[base + s];
    out[base + s] = v - ri - rowsum[b * Dn + j] * inv + itot;
  }
}

extern "C" void kernel_launch(void* const* d_in, const int* in_sizes, int n_in,
                              void* d_out, int out_size, void* d_ws, size_t ws_size,
                              hipStream_t stream) {
  const float* x = (const float*)d_in[0];
  const float* t = (const float*)d_in[1];
  float* out = (float*)d_out;
  float* rowsum = (float*)d_ws;                  // [256][512] f32
  float* tot = rowsum + Bn * Dn;                 // [256] f32

  hipMemsetAsync(rowsum, 0, Bn * Dn * sizeof(float), stream);
  hipLaunchKernelGGL(k1_gram_dcov, dim3(1024), dim3(256), 0, stream, x, t, out, rowsum);
  hipLaunchKernelGGL(k2a_tot, dim3(Bn), dim3(256), 0, stream, rowsum, tot);
  hipLaunchKernelGGL(k2_center, dim3(Dn, Bn), dim3(256), 0, stream, out, rowsum, tot);
}

// Round 3
// 350.095 us; speedup vs baseline: 1.6490x; 1.6490x over previous
//
#include <hip/hip_runtime.h>
#include <hip/hip_bf16.h>
#include <math.h>

#define Bn 256
#define Mn 196
#define Dn 512
#define Mstr 232      // LDS col stride (shorts): 464B = 29 x 16B granules (odd) -> full bank spread for b128
#define TILE 128
#define OUTB 131328   // 512*513/2

typedef __attribute__((ext_vector_type(8))) short bf16x8;
typedef __attribute__((ext_vector_type(4))) float f32x4;

__device__ __forceinline__ unsigned short f2bf(float f) {
  unsigned u = __float_as_uint(f);
  unsigned r = u + 0x7fffu + ((u >> 16) & 1u);
  return (unsigned short)(r >> 16);
}

// Stage a 128-col panel of x_b transposed into LDS as bf16 [col][m] (m padded to 224),
// 16B ds_write per thread-chunk. Also per-thread partial sum of x^2 for the diag.
// 1024 threads: thread -> col c = tid&127, m-chunks mc = (tid>>7) + 8*it.
__device__ __forceinline__ void stage_panel(short* __restrict__ lds,
                                            float* __restrict__ dtmp,
                                            const float* __restrict__ xb,
                                            int c0, int tid) {
  const int c = tid & 127;
  float dacc = 0.f;
  #pragma unroll
  for (int it = 0; it < 4; ++it) {
    const int mc = (tid >> 7) + 8 * it;   // 0..31, use 0..27
    if (mc < 28) {
      const int m0 = mc * 8;
      float xv[8];
      #pragma unroll
      for (int u = 0; u < 8; ++u) {
        const int m = m0 + u;
        xv[u] = (m < Mn) ? xb[(size_t)m * Dn + c0 + c] : 0.f;
        dacc += xv[u] * xv[u];
      }
      uint4 pk;
      pk.x = ((unsigned)f2bf(xv[1]) << 16) | (unsigned)f2bf(xv[0]);
      pk.y = ((unsigned)f2bf(xv[3]) << 16) | (unsigned)f2bf(xv[2]);
      pk.z = ((unsigned)f2bf(xv[5]) << 16) | (unsigned)f2bf(xv[4]);
      pk.w = ((unsigned)f2bf(xv[7]) << 16) | (unsigned)f2bf(xv[6]);
      *reinterpret_cast<uint4*>(&lds[c * Mstr + m0]) = pk;
    }
  }
  dtmp[tid] = dacc;   // [part][col] layout: part = tid>>7
}

__global__ __launch_bounds__(1024)
void k1_gram_dcov(const float* __restrict__ x, const float* __restrict__ tptr,
                  float* __restrict__ out, float* __restrict__ rowsum) {
  __shared__ short ldsI[TILE * Mstr];
  __shared__ short ldsJ[TILE * Mstr];
  __shared__ float dtmp[1024];
  __shared__ float dI[TILE];
  __shared__ float dJ[TILE];

  const int tid = threadIdx.x;
  const int bid = blockIdx.x;
  const int ti  = bid >> 8;    // 0..3 (one of each ti lands per CU -> balanced)
  const int b   = bid & 255;
  const float* xb = x + (size_t)b * Mn * Dn;
  const float et = expf(tptr[0]);

  stage_panel(ldsI, dtmp, xb, ti * TILE, tid);
  __syncthreads();
  if (tid < TILE) {
    float s = 0.f;
    #pragma unroll
    for (int p = 0; p < 8; ++p) s += dtmp[p * 128 + tid];
    dI[tid] = s;
  }
  __syncthreads();

  const int lane = tid & 63;
  const int wid  = tid >> 6;               // 0..15
  const int wi = wid >> 2, wj = wid & 3;   // 4x4 waves of 32x32
  const int lr = lane & 15, lg = lane >> 4;
  const size_t outb = (size_t)b * OUTB;

  for (int tj = ti; tj < 4; ++tj) {
    const short* Bp;
    const float* dJv;
    if (tj > ti) {
      stage_panel(ldsJ, dtmp, xb, tj * TILE, tid);
      __syncthreads();
      if (tid < TILE) {
        float s = 0.f;
        #pragma unroll
        for (int p = 0; p < 8; ++p) s += dtmp[p * 128 + tid];
        dJ[tid] = s;
      }
      __syncthreads();
      Bp = ldsJ; dJv = dJ;
    } else {
      Bp = ldsI; dJv = dI;
    }

    // ---- MFMA: 32x32 per wave, K = 224 ----
    f32x4 acc[2][2];
    #pragma unroll
    for (int a = 0; a < 2; ++a)
      #pragma unroll
      for (int c = 0; c < 2; ++c) acc[a][c] = (f32x4){0.f, 0.f, 0.f, 0.f};

    #pragma unroll
    for (int kk = 0; kk < 7; ++kk) {
      const int k0 = kk * 32 + lg * 8;
      bf16x8 af[2], bfr[2];
      #pragma unroll
      for (int mi = 0; mi < 2; ++mi)
        af[mi] = *reinterpret_cast<const bf16x8*>(&ldsI[(wi * 32 + mi * 16 + lr) * Mstr + k0]);
      #pragma unroll
      for (int nj = 0; nj < 2; ++nj)
        bfr[nj] = *reinterpret_cast<const bf16x8*>(&Bp[(wj * 32 + nj * 16 + lr) * Mstr + k0]);
      #pragma unroll
      for (int mi = 0; mi < 2; ++mi)
        #pragma unroll
        for (int nj = 0; nj < 2; ++nj)
          acc[mi][nj] = __builtin_amdgcn_mfma_f32_16x16x32_bf16(af[mi], bfr[nj], acc[mi][nj], 0, 0, 0);
    }

    // ---- epilogue: dcov, triu store, symmetric row/col sum accumulation ----
    float colAcc[2] = {0.f, 0.f};
    #pragma unroll
    for (int mi = 0; mi < 2; ++mi) {
      #pragma unroll
      for (int reg = 0; reg < 4; ++reg) {
        const int iloc = wi * 32 + mi * 16 + lg * 4 + reg;
        const int ig = ti * TILE + iloc;
        float rowAcc = 0.f;
        #pragma unroll
        for (int nj = 0; nj < 2; ++nj) {
          const int jloc = wj * 32 + nj * 16 + lr;
          const int jg = tj * TILE + jloc;
          float g = acc[mi][nj][reg];
          float raw = dI[iloc] + dJv[jloc] - 2.f * g;
          raw = fmaxf(raw, 0.f);
          if (ig == jg) raw = 0.f;                 // exact-0 diagonal (matches reference)
          const float v = sqrtf(et * raw + 1e-5f);
          if (ig <= jg) {
            const int off = ig * Dn - (ig * (ig - 1)) / 2;
            out[outb + off + (jg - ig)] = v;
            rowAcc += v;                           // row i gets all j>=i on this tile
            if (ig < jg) colAcc[nj] += v;          // col j gets strict-upper (symmetry)
          }
        }
        rowAcc += __shfl_xor(rowAcc, 1);
        rowAcc += __shfl_xor(rowAcc, 2);
        rowAcc += __shfl_xor(rowAcc, 4);
        rowAcc += __shfl_xor(rowAcc, 8);
        if (lr == 0) atomicAdd(&rowsum[b * Dn + ig], rowAcc);
      }
    }
    #pragma unroll
    for (int nj = 0; nj < 2; ++nj) {
      float cs = colAcc[nj];
      cs += __shfl_xor(cs, 16);
      cs += __shfl_xor(cs, 32);
      if (lg == 0) {
        const int jg = tj * TILE + wj * 32 + nj * 16 + lr;
        atomicAdd(&rowsum[b * Dn + jg], cs);
      }
    }
    __syncthreads();   // protect ldsJ/dtmp before next stage
  }
}

__global__ __launch_bounds__(256)
void k2a_tot(const float* __restrict__ rowsum, float* __restrict__ tot) {
  const int b = blockIdx.x;
  const int t = threadIdx.x;
  float v = rowsum[b * Dn + t] + rowsum[b * Dn + t + 256];
  #pragma unroll
  for (int m = 1; m < 64; m <<= 1) v += __shfl_xor(v, m);
  __shared__ float w[4];
  if ((t & 63) == 0) w[t >> 6] = v;
  __syncthreads();
  if (t == 0) tot[b] = w[0] + w[1] + w[2] + w[3];
}

__global__ __launch_bounds__(256)
void k2_center(float* __restrict__ out, const float* __restrict__ rowsum,
               const float* __restrict__ tot) {
  const float inv = 1.f / 512.f;
  const int t = threadIdx.x;
  for (int r = blockIdx.x; r < Bn * Dn; r += gridDim.x) {
    const int b = r >> 9, i = r & 511;
    const float c0 = tot[b] * (1.f / (512.f * 512.f)) - rowsum[b * Dn + i] * inv;
    const int L = Dn - i;
    const size_t base = (size_t)b * OUTB + (size_t)(i * Dn - (i * (i - 1)) / 2);
    float* p = out + base;
    const float* rs = rowsum + b * Dn + i;
    int head = (int)((4 - (base & 3)) & 3);
    if (head > L) head = L;
    if (t < head) p[t] += c0 - rs[t] * inv;
    const int nb = (L - head) >> 2;
    for (int q = t; q < nb; q += 256) {
      const int s = head + q * 4;
      float4 v = *reinterpret_cast<float4*>(p + s);
      v.x += c0 - rs[s]     * inv;
      v.y += c0 - rs[s + 1] * inv;
      v.z += c0 - rs[s + 2] * inv;
      v.w += c0 - rs[s + 3] * inv;
      *reinterpret_cast<float4*>(p + s) = v;
    }
    const int s2 = head + nb * 4 + t;
    if (s2 < L) p[s2] += c0 - rs[s2] * inv;
  }
}

extern "C" void kernel_launch(void* const* d_in, const int* in_sizes, int n_in,
                              void* d_out, int out_size, void* d_ws, size_t ws_size,
                              hipStream_t stream) {
  const float* x = (const float*)d_in[0];
  const float* t = (const float*)d_in[1];
  float* out = (float*)d_out;
  float* rowsum = (float*)d_ws;                  // [256][512] f32
  float* tot = rowsum + Bn * Dn;                 // [256] f32

  hipMemsetAsync(rowsum, 0, Bn * Dn * sizeof(float), stream);
  hipLaunchKernelGGL(k1_gram_dcov, dim3(1024), dim3(1024), 0, stream, x, t, out, rowsum);
  hipLaunchKernelGGL(k2a_tot, dim3(Bn), dim3(256), 0, stream, rowsum, tot);
  hipLaunchKernelGGL(k2_center, dim3(4096), dim3(256), 0, stream, out, rowsum, tot);
}